// Round 7
// baseline (129.530 us; speedup 1.0000x reference)
//
#include <hip/hip_runtime.h>
#include <math.h>

// Tropical bottleneck network, fp32.
// Activations chunked-transposed [K/4][1024][4]; lane = batch b.
// W staged to LDS once per block, read broadcast (ds_read_b128).
// R7 = R5's PROVEN sync structure (2 row-waves x 4-way K-split, single LDS
// combine, 11 launches, no in-place RMW within a dispatch) + BT=4 batch
// tiling: block = 8 rows x 256 batch, so each W ds_read feeds 4x the VALU
// work (DS was the R5 limiter; DS and VALU now balanced per the cycle model).

#define BALL 1024

struct Job {
    const float* X;    // chunked [K/4][1024][4]
    const float* W;    // [rows][K] row-major
    const float* bias; // [rows] (max stages only)
    const float* E1;   // chunked, min-combine, or nullptr
    const float* E2;   // chunked, max-combine, or nullptr
    float* Y;          // chunked [rows/4][1024][4]
};

#define RD(x, y) (IS_MAX ? fmaxf((x), (y)) : fminf((x), (y)))

// accumulate 4 rows x 4 b-tiles over chunks [kcB, kcB+K/16)
template<int IS_MAX, int K>
__device__ __forceinline__ void accum4(
    const float4* __restrict__ Xb,      // j.X (as float4) + b0 + lane
    const float4* __restrict__ Wrow,    // LDS W base for this wave's 4 rows
    int kcB, float (&acc)[4][4])
{
    constexpr int CQ = K / 16;          // chunks per K-quarter
    {   // peel first chunk: initializes acc, no +-INF
        float4 xv[4];
#pragma unroll
        for (int bt = 0; bt < 4; ++bt) xv[bt] = Xb[(size_t)kcB * BALL + bt * 64];
#pragma unroll
        for (int r = 0; r < 4; ++r) {
            float4 w = Wrow[r * (K / 4) + kcB];
#pragma unroll
            for (int bt = 0; bt < 4; ++bt)
                acc[r][bt] = RD(RD(xv[bt].x + w.x, xv[bt].y + w.y),
                                RD(xv[bt].z + w.z, xv[bt].w + w.w));
        }
    }
#pragma unroll 2
    for (int kc = kcB + 1; kc < kcB + CQ; ++kc) {
        float4 xv[4];
#pragma unroll
        for (int bt = 0; bt < 4; ++bt) xv[bt] = Xb[(size_t)kc * BALL + bt * 64];
#pragma unroll
        for (int r = 0; r < 4; ++r) {
            float4 w = Wrow[r * (K / 4) + kc];
#pragma unroll
            for (int bt = 0; bt < 4; ++bt)   // fuses to v_min3/v_max3 pairs
                acc[r][bt] = RD(RD(RD(RD(xv[bt].x + w.x, xv[bt].y + w.y),
                                      xv[bt].z + w.z), xv[bt].w + w.w), acc[r][bt]);
        }
    }
}

// 512 threads = 8 waves = 2 row-waves (4 rows each) x 4 K-quarters.
// Block = 8 output rows x 256 batch.
template<int IS_MAX, int K>
__device__ __forceinline__ void run_job(
    const Job j, int by, float4* __restrict__ Wl4,
    float (* __restrict__ part)[8][256])
{
    const int tid  = threadIdx.x;
    const int lane = tid & 63;
    const int wv   = tid >> 6;        // 0..7
    const int rw   = wv & 1;          // row-wave
    const int q    = wv >> 1;         // K-quarter
    const int b0   = blockIdx.x * 256;
    const int i0   = by * 8;
    const int r0   = rw * 4;

    // stage W[8 rows][K] into LDS (2K floats = K/2 float4s), coalesced
    const float4* Wg = (const float4*)(j.W + (size_t)i0 * K);
    if constexpr (K == 512) {
        Wl4[tid]       = Wg[tid];
        Wl4[tid + 512] = Wg[tid + 512];
    } else {                           // K=256: 512 float4s
        Wl4[tid] = Wg[tid];
    }
    __syncthreads();

    float acc[4][4];
    accum4<IS_MAX, K>((const float4*)j.X + b0 + lane,
                      Wl4 + (size_t)r0 * (K / 4), q * (K / 16), acc);

    if (q) {
#pragma unroll
        for (int r = 0; r < 4; ++r)
#pragma unroll
            for (int bt = 0; bt < 4; ++bt)
                part[q - 1][r0 + r][bt * 64 + lane] = acc[r][bt];
    }
    __syncthreads();
    if (q == 0) {
#pragma unroll
        for (int qq = 0; qq < 3; ++qq)
#pragma unroll
            for (int r = 0; r < 4; ++r)
#pragma unroll
                for (int bt = 0; bt < 4; ++bt)
                    acc[r][bt] = RD(acc[r][bt], part[qq][r0 + r][bt * 64 + lane]);

        const int c0 = (i0 + r0) >> 2;      // this wave's output chunk
        float4 bb;
        if (IS_MAX) bb = *(const float4*)(j.bias + i0 + r0);
#pragma unroll
        for (int bt = 0; bt < 4; ++bt) {
            const int b = b0 + bt * 64 + lane;
            float4 v = make_float4(acc[0][bt], acc[1][bt], acc[2][bt], acc[3][bt]);
            if (IS_MAX) { v.x += bb.x; v.y += bb.y; v.z += bb.z; v.w += bb.w; }
            if (j.E1) {
                float4 e = ((const float4*)j.E1)[(size_t)c0 * BALL + b];
                v.x = fminf(v.x, e.x); v.y = fminf(v.y, e.y);
                v.z = fminf(v.z, e.z); v.w = fminf(v.w, e.w);
            }
            if (j.E2) {
                float4 e = ((const float4*)j.E2)[(size_t)c0 * BALL + b];
                v.x = fmaxf(v.x, e.x); v.y = fmaxf(v.y, e.y);
                v.z = fmaxf(v.z, e.z); v.w = fmaxf(v.w, e.w);
            }
            ((float4*)j.Y)[(size_t)c0 * BALL + b] = v;
        }
    }
}

// Two jobs per launch: blocks with blockIdx.y < nbyA run ja (K=KA), rest jb (K=KB).
template<int IS_MAX, int KA, int KB>
__global__ __launch_bounds__(512) void tsemi(Job ja, Job jb, int nbyA)
{
    constexpr int KM = (KA > KB) ? KA : KB;
    __shared__ __align__(16) float Wl[8 * KM];
    __shared__ float part[3][8][256];
    const int by = blockIdx.y;
    if (by < nbyA) run_job<IS_MAX, KA>(ja, by, (float4*)Wl, part);
    else           run_job<IS_MAX, KB>(jb, by - nbyA, (float4*)Wl, part);
}

// x [1024][256] -> Xc chunked [64][1024][4]
__global__ __launch_bounds__(256) void t_in(const float* __restrict__ x,
                                            float* __restrict__ Xc)
{
    __shared__ float s[64][65];
    const int lane = threadIdx.x & 63;
    const int ty   = threadIdx.x >> 6;
    const int b0   = blockIdx.x * 64;
    const int k0   = blockIdx.y * 64;
#pragma unroll
    for (int r = ty; r < 64; r += 4)
        s[r][lane] = x[(size_t)(b0 + r) * 256 + k0 + lane];
    __syncthreads();
    float4* X4 = (float4*)Xc;
#pragma unroll
    for (int cc = 0; cc < 4; ++cc) {
        int c = ty * 4 + cc;
        float4 v = make_float4(s[lane][c * 4 + 0], s[lane][c * 4 + 1],
                               s[lane][c * 4 + 2], s[lane][c * 4 + 3]);
        X4[(size_t)(k0 / 4 + c) * BALL + b0 + lane] = v;
    }
}

// Zc chunked [128][1024][4] (512 rows) -> out [1024][512]
__global__ __launch_bounds__(256) void t_out(const float* __restrict__ Zc,
                                             float* __restrict__ out)
{
    __shared__ float s[64][65];
    const int lane = threadIdx.x & 63;
    const int ty   = threadIdx.x >> 6;
    const int i0   = blockIdx.x * 64;
    const int b0   = blockIdx.y * 64;
    const float4* Z4 = (const float4*)Zc;
#pragma unroll
    for (int cc = 0; cc < 4; ++cc) {
        int c = ty * 4 + cc;
        float4 v = Z4[(size_t)(i0 / 4 + c) * BALL + b0 + lane];
        s[lane][c * 4 + 0] = v.x; s[lane][c * 4 + 1] = v.y;
        s[lane][c * 4 + 2] = v.z; s[lane][c * 4 + 3] = v.w;
    }
    __syncthreads();
#pragma unroll
    for (int r = ty; r < 64; r += 4)
        out[(size_t)(b0 + r) * 512 + i0 + lane] = s[r][lane];
}

extern "C" void kernel_launch(void* const* d_in, const int* in_sizes, int n_in,
                              void* d_out, int out_size, void* d_ws, size_t ws_size,
                              hipStream_t stream) {
    const float* x      = (const float*)d_in[0];
    const float* l1_w1  = (const float*)d_in[1];
    const float* l1_w2  = (const float*)d_in[2];
    const float* l1_b2  = (const float*)d_in[3];
    const float* l2_w1  = (const float*)d_in[4];
    const float* l2_w2  = (const float*)d_in[5];
    const float* l2_b2  = (const float*)d_in[6];
    const float* l3_w1  = (const float*)d_in[7];
    const float* l3_w2  = (const float*)d_in[8];
    const float* l3_b2  = (const float*)d_in[9];
    const float* l4_w1  = (const float*)d_in[10];
    const float* l4_w2  = (const float*)d_in[11];
    const float* l4_b2  = (const float*)d_in[12];
    const float* l4_sw1 = (const float*)d_in[13];
    const float* l4_sw2 = (const float*)d_in[14];
    const float* l4_sb2 = (const float*)d_in[15];
    const float* sc_w1  = (const float*)d_in[16];
    const float* sc_w2  = (const float*)d_in[17];
    const float* sc_b2  = (const float*)d_in[18];
    (void)in_sizes; (void)n_in; (void)ws_size; (void)out_size;

    float* out = (float*)d_out;
    float* ws  = (float*)d_ws;

    // workspace (floats), 7.0 MB peak (R5-proven layout):
    float* Xc    = ws;             // 1 MB
    float* M     = ws + 262144;    // 1 MB
    float* A     = ws + 524288;    // 1 MB
    float* SC0   = ws + 786432;    // 2 MB
    float* SCout = ws + 1310720;   // 2 MB
    // lifetime-disjoint aliases:
    float* X2 = Xc;                // layer-2 output (Xc dead after stage 3)
    float* T  = SC0;               // layer-4 main pre-act (SC0 dead after stage 3)
    float* T2 = ws;                // layer-4 shortcut pre-act, 2 MB over [Xc,M]
    float* Zf = SC0;               // final chunked result (T dead after stage 9)
    float* O4 = out;               // d_out doubles as scratch (chunked), dead
                                   // before t_out overwrites it

    dim3 blk(512);

    // 1. x -> chunked Xc
    t_in<<<dim3(16, 4), 256, 0, stream>>>(x, Xc);

    // 2. merged min-plus: {Xc,l1_w1 -> M (256r)} + {Xc,sc_w1 -> SC0 (512r)}
    tsemi<0, 256, 256><<<dim3(4, 96), blk, 0, stream>>>(
        Job{Xc, l1_w1, nullptr, nullptr, nullptr, M},
        Job{Xc, sc_w1, nullptr, nullptr, nullptr, SC0}, 32);

    // 3. merged max-plus: {M,l1_w2,b2, min Xc -> A} + {SC0,sc_w2,sc_b2 -> SCout}
    tsemi<1, 256, 512><<<dim3(4, 96), blk, 0, stream>>>(
        Job{M, l1_w2, l1_b2, Xc, nullptr, A},
        Job{SC0, sc_w2, sc_b2, nullptr, nullptr, SCout}, 32);

    // 4-7. layers 2 and 3 (single job; all blocks take branch A)
    tsemi<0, 256, 256><<<dim3(4, 32), blk, 0, stream>>>(
        Job{A, l2_w1, nullptr, nullptr, nullptr, M},
        Job{A, l2_w1, nullptr, nullptr, nullptr, M}, 32);
    tsemi<1, 256, 256><<<dim3(4, 32), blk, 0, stream>>>(
        Job{M, l2_w2, l2_b2, A, nullptr, X2},
        Job{M, l2_w2, l2_b2, A, nullptr, X2}, 32);
    tsemi<0, 256, 256><<<dim3(4, 32), blk, 0, stream>>>(
        Job{X2, l3_w1, nullptr, nullptr, nullptr, M},
        Job{X2, l3_w1, nullptr, nullptr, nullptr, M}, 32);
    tsemi<1, 256, 256><<<dim3(4, 32), blk, 0, stream>>>(
        Job{M, l3_w2, l3_b2, X2, nullptr, A},
        Job{M, l3_w2, l3_b2, X2, nullptr, A}, 32);          // A = x3

    // 8. merged layer-4 min-plus: {A,l4_w1 -> T} + {A,l4_sw1 -> T2} (512r each)
    tsemi<0, 256, 256><<<dim3(4, 128), blk, 0, stream>>>(
        Job{A, l4_w1,  nullptr, nullptr, nullptr, T},
        Job{A, l4_sw1, nullptr, nullptr, nullptr, T2}, 64);

    // 9. layer-4 main max-plus -> O4 (staged in d_out, chunked)
    tsemi<1, 512, 512><<<dim3(4, 64), blk, 0, stream>>>(
        Job{T, l4_w2, l4_b2, nullptr, nullptr, O4},
        Job{T, l4_w2, l4_b2, nullptr, nullptr, O4}, 64);

    // 10. layer-4 shortcut max-plus, min with O4, max with SCout -> Zf
    tsemi<1, 512, 512><<<dim3(4, 64), blk, 0, stream>>>(
        Job{T2, l4_sw2, l4_sb2, O4, SCout, Zf},
        Job{T2, l4_sw2, l4_sb2, O4, SCout, Zf}, 64);

    // 11. un-transpose Zf -> out
    t_out<<<dim3(8, 16), 256, 0, stream>>>(Zf, out);
}